// Round 1
// baseline (5858.310 us; speedup 1.0000x reference)
//
#include <hip/hip_runtime.h>

#define HID 256
#define T_STEPS 1024
#define F_IN 40
#define NSPK 1251
#define NCHUNK 8            // workgroups per layer
#define NBLOCKS (3 * NCHUNK)
#define K2_THREADS 512

// workspace layout (floats): hbuf[3][1025][256], then done[3][1025] (u32)
#define HBUF_FLOATS (3 * 1025 * 256)
#define DONE_OFF_BYTES (HBUF_FLOATS * 4)

__device__ __forceinline__ float fast_sig(float v) {
    return __builtin_amdgcn_rcpf(1.f + __expf(-v));
}
__device__ __forceinline__ float fast_tanh(float v) {
    return 2.f * __builtin_amdgcn_rcpf(1.f + __expf(-2.f * v)) - 1.f;
}

// ---------------- K0: init flags + h0 ----------------
__global__ void k0_init(float* __restrict__ hbuf, unsigned* __restrict__ done) {
    int tid = threadIdx.x;
    // zero h[l][0][:]
    if (tid < 3 * HID) {
        int l = tid / HID, k = tid % HID;
        hbuf[(l * 1025 + 0) * HID + k] = 0.f;
    }
    // done[l][s]: s==0 pre-completed (G chunks), rest 0
    for (int i = tid; i < 3 * 1025; i += blockDim.x) {
        done[i] = ((i % 1025) == 0) ? (unsigned)NCHUNK : 0u;
    }
}

// ---------------- K2: pipelined 3-layer LSTM (persistent, flag-synced) ----------------
__global__ __launch_bounds__(K2_THREADS) void k2_lstm(
    const float* __restrict__ x,
    const float* __restrict__ w_ih0, const float* __restrict__ w_hh0,
    const float* __restrict__ b_ih0, const float* __restrict__ b_hh0,
    const float* __restrict__ w_ih1, const float* __restrict__ w_hh1,
    const float* __restrict__ b_ih1, const float* __restrict__ b_hh1,
    const float* __restrict__ w_ih2, const float* __restrict__ w_hh2,
    const float* __restrict__ b_ih2, const float* __restrict__ b_hh2,
    float* __restrict__ hbuf, unsigned* __restrict__ done)
{
    const int bid = blockIdx.x;
    const int layer = bid / NCHUNK;      // 0..2
    const int g     = bid % NCHUNK;      // chunk of 32 h-indices
    const int tid   = threadIdx.x;
    const int row_idx = tid >> 2;        // 0..127 : (gate q, local j)
    const int seg     = tid & 3;         // k-segment 0..3 (128 wide each)
    const int q  = row_idx >> 5;         // gate 0..3 (i,f,g,o)
    const int jj = row_idx & 31;
    const int r  = q * 256 + g * 32 + jj;  // global gate row 0..1023

    const float* wih = (layer == 0) ? w_ih0 : (layer == 1) ? w_ih1 : w_ih2;
    const float* whh = (layer == 0) ? w_hh0 : (layer == 1) ? w_hh1 : w_hh2;
    const float* bih = (layer == 0) ? b_ih0 : (layer == 1) ? b_ih1 : b_ih2;
    const float* bhh = (layer == 0) ? b_hh0 : (layer == 1) ? b_hh1 : b_hh2;

    __shared__ float lds_in[512];     // [0:256] = x-in (prev layer h / x row), [256:512] = h_prev
    __shared__ float lds_gate[128];

    // ---- load this thread's 128 weights into registers ----
    float w[128];
    if (seg >= 2) {
        const float4* src = (const float4*)(whh + r * HID + (seg - 2) * 128);
        #pragma unroll
        for (int k4 = 0; k4 < 32; k4++) {
            float4 v = src[k4];
            w[k4 * 4 + 0] = v.x; w[k4 * 4 + 1] = v.y;
            w[k4 * 4 + 2] = v.z; w[k4 * 4 + 3] = v.w;
        }
    } else if (layer > 0) {
        const float4* src = (const float4*)(wih + r * HID + seg * 128);
        #pragma unroll
        for (int k4 = 0; k4 < 32; k4++) {
            float4 v = src[k4];
            w[k4 * 4 + 0] = v.x; w[k4 * 4 + 1] = v.y;
            w[k4 * 4 + 2] = v.z; w[k4 * 4 + 3] = v.w;
        }
    } else {
        // layer 0: seg0 holds the 40-wide x-projection row, seg1 is all-zero
        #pragma unroll
        for (int k = 0; k < 128; k++) w[k] = 0.f;
        if (seg == 0) {
            for (int k = 0; k < F_IN; k++) w[k] = w_ih0[r * F_IN + k];
        }
    }
    float bias = (seg == 0) ? (bih[r] + bhh[r]) : 0.f;

    for (int i = tid; i < 512; i += K2_THREADS) lds_in[i] = 0.f;
    __syncthreads();

    const float* x63 = x + 63 * T_STEPS * F_IN;
    unsigned* done_prev = done + (layer - 1) * 1025;   // only deref'd when layer>0
    unsigned* done_own  = done + layer * 1025;
    const float* h_prev_layer = hbuf + (layer - 1) * 1025 * HID;
    float* h_own              = hbuf + layer * 1025 * HID;

    float c_state = 0.f;   // valid for tid < 32 (h-index g*32+tid)

    for (int t = 0; t < T_STEPS; t++) {
        // ---- wait for inputs ----
        if (tid == 0) {
            if (layer > 0) {
                while (__hip_atomic_load(&done_prev[t + 1], __ATOMIC_ACQUIRE,
                                         __HIP_MEMORY_SCOPE_AGENT) != (unsigned)NCHUNK) {}
            }
            if (t > 0) {
                while (__hip_atomic_load(&done_own[t], __ATOMIC_ACQUIRE,
                                         __HIP_MEMORY_SCOPE_AGENT) != (unsigned)NCHUNK) {}
            }
        }
        __syncthreads();

        // ---- stage inputs into LDS ----
        if (layer == 0) {
            if (tid < 10)   // 40 floats of x[63][t][:]
                ((float4*)lds_in)[tid] = ((const float4*)(x63 + t * F_IN))[tid];
        } else {
            if (tid < 64)
                ((float4*)lds_in)[tid] = ((const float4*)(h_prev_layer + (t + 1) * HID))[tid];
        }
        if (tid >= 64 && tid < 128)
            ((float4*)(lds_in + 256))[tid - 64] = ((const float4*)(h_own + t * HID))[tid - 64];
        __syncthreads();

        // ---- 128-wide partial dot per thread, weights in VGPRs ----
        float acc = 0.f;
        const float* in = lds_in + seg * 128;
        #pragma unroll
        for (int k = 0; k < 128; k++) acc += w[k] * in[k];
        acc += __shfl_xor(acc, 1, 64);
        acc += __shfl_xor(acc, 2, 64);
        if (seg == 0) lds_gate[row_idx] = acc + bias;
        __syncthreads();

        // ---- gate nonlinearity + state update (32 threads) ----
        if (tid < 32) {
            float gi = lds_gate[tid];
            float gf = lds_gate[32 + tid];
            float gg = lds_gate[64 + tid];
            float go = lds_gate[96 + tid];
            float si = fast_sig(gi);
            float sf = fast_sig(gf);
            float so = fast_sig(go);
            c_state = sf * c_state + si * fast_tanh(gg);
            float hv = so * fast_tanh(c_state);
            h_own[(t + 1) * HID + g * 32 + tid] = hv;
        }
        __threadfence();
        __syncthreads();
        if (tid == 0) {
            __hip_atomic_fetch_add(&done_own[t + 1], 1u, __ATOMIC_RELEASE,
                                   __HIP_MEMORY_SCOPE_AGENT);
        }
    }
}

// ---------------- K3: logits = h2 @ w_lin^T + b_lin (tiled fp32 GEMM) ----------------
#define BM 64
#define BN 64
#define BK 32
__global__ __launch_bounds__(256) void k3_logits(
    const float* __restrict__ hbuf, const float* __restrict__ w_lin,
    const float* __restrict__ b_lin, float* __restrict__ out)
{
    const float* A = hbuf + (2 * 1025 + 1) * HID;   // A[t][k], stride 256
    int m0 = blockIdx.x * BM;
    int n0 = blockIdx.y * BN;
    int tid = threadIdx.x;
    __shared__ float As[BM][BK + 1];
    __shared__ float Bs[BN][BK + 1];
    float accv[4][4] = {};
    int tx = tid % 16, ty = tid / 16;

    for (int k0 = 0; k0 < HID; k0 += BK) {
        int row = tid / 4;
        int kq  = (tid % 4) * 8;
        {
            const float4* src = (const float4*)(A + (m0 + row) * HID + k0 + kq);
            float4 v0 = src[0], v1 = src[1];
            As[row][kq + 0] = v0.x; As[row][kq + 1] = v0.y; As[row][kq + 2] = v0.z; As[row][kq + 3] = v0.w;
            As[row][kq + 4] = v1.x; As[row][kq + 5] = v1.y; As[row][kq + 6] = v1.z; As[row][kq + 7] = v1.w;
        }
        {
            int n = n0 + row;
            float4 v0 = make_float4(0.f, 0.f, 0.f, 0.f), v1 = v0;
            if (n < NSPK) {
                const float4* src = (const float4*)(w_lin + n * HID + k0 + kq);
                v0 = src[0]; v1 = src[1];
            }
            Bs[row][kq + 0] = v0.x; Bs[row][kq + 1] = v0.y; Bs[row][kq + 2] = v0.z; Bs[row][kq + 3] = v0.w;
            Bs[row][kq + 4] = v1.x; Bs[row][kq + 5] = v1.y; Bs[row][kq + 6] = v1.z; Bs[row][kq + 7] = v1.w;
        }
        __syncthreads();
        #pragma unroll
        for (int kk = 0; kk < BK; kk++) {
            float a0 = As[ty * 4 + 0][kk], a1 = As[ty * 4 + 1][kk];
            float a2 = As[ty * 4 + 2][kk], a3 = As[ty * 4 + 3][kk];
            float b0 = Bs[tx * 4 + 0][kk], b1 = Bs[tx * 4 + 1][kk];
            float b2 = Bs[tx * 4 + 2][kk], b3 = Bs[tx * 4 + 3][kk];
            accv[0][0] += a0 * b0; accv[0][1] += a0 * b1; accv[0][2] += a0 * b2; accv[0][3] += a0 * b3;
            accv[1][0] += a1 * b0; accv[1][1] += a1 * b1; accv[1][2] += a1 * b2; accv[1][3] += a1 * b3;
            accv[2][0] += a2 * b0; accv[2][1] += a2 * b1; accv[2][2] += a2 * b2; accv[2][3] += a2 * b3;
            accv[3][0] += a3 * b0; accv[3][1] += a3 * b1; accv[3][2] += a3 * b2; accv[3][3] += a3 * b3;
        }
        __syncthreads();
    }
    #pragma unroll
    for (int i = 0; i < 4; i++) {
        int m = m0 + ty * 4 + i;
        #pragma unroll
        for (int j = 0; j < 4; j++) {
            int n = n0 + tx * 4 + j;
            if (n < NSPK) out[(size_t)m * NSPK + n] = accv[i][j] + b_lin[n];
        }
    }
}

// ---------------- K4: in-place row-wise log_softmax over NSPK ----------------
__global__ __launch_bounds__(256) void k4_logsoftmax(float* __restrict__ out)
{
    int t = blockIdx.x;
    float* row = out + (size_t)t * NSPK;
    int tid = threadIdx.x;
    __shared__ float red[8];
    float vals[5];
    float lmax = -1e30f;
    #pragma unroll
    for (int k = 0; k < 5; k++) {
        int n = tid + k * 256;
        vals[k] = (n < NSPK) ? row[n] : -1e30f;
        lmax = fmaxf(lmax, vals[k]);
    }
    #pragma unroll
    for (int m = 1; m < 64; m <<= 1) lmax = fmaxf(lmax, __shfl_xor(lmax, m, 64));
    int wave = tid >> 6;
    if ((tid & 63) == 0) red[wave] = lmax;
    __syncthreads();
    float gmax = fmaxf(fmaxf(red[0], red[1]), fmaxf(red[2], red[3]));
    float lsum = 0.f;
    #pragma unroll
    for (int k = 0; k < 5; k++) {
        int n = tid + k * 256;
        if (n < NSPK) lsum += __expf(vals[k] - gmax);
    }
    #pragma unroll
    for (int m = 1; m < 64; m <<= 1) lsum += __shfl_xor(lsum, m, 64);
    if ((tid & 63) == 0) red[4 + wave] = lsum;
    __syncthreads();
    float lse = logf(red[4] + red[5] + red[6] + red[7]) + gmax;
    #pragma unroll
    for (int k = 0; k < 5; k++) {
        int n = tid + k * 256;
        if (n < NSPK) row[n] = vals[k] - lse;
    }
}

extern "C" void kernel_launch(void* const* d_in, const int* in_sizes, int n_in,
                              void* d_out, int out_size, void* d_ws, size_t ws_size,
                              hipStream_t stream) {
    const float* x     = (const float*)d_in[0];
    const float* w_ih0 = (const float*)d_in[1];
    const float* w_hh0 = (const float*)d_in[2];
    const float* b_ih0 = (const float*)d_in[3];
    const float* b_hh0 = (const float*)d_in[4];
    const float* w_ih1 = (const float*)d_in[5];
    const float* w_hh1 = (const float*)d_in[6];
    const float* b_ih1 = (const float*)d_in[7];
    const float* b_hh1 = (const float*)d_in[8];
    const float* w_ih2 = (const float*)d_in[9];
    const float* w_hh2 = (const float*)d_in[10];
    const float* b_ih2 = (const float*)d_in[11];
    const float* b_hh2 = (const float*)d_in[12];
    const float* w_lin = (const float*)d_in[13];
    const float* b_lin = (const float*)d_in[14];

    float* hbuf    = (float*)d_ws;
    unsigned* done = (unsigned*)((char*)d_ws + DONE_OFF_BYTES);
    float* out     = (float*)d_out;

    k0_init<<<1, 1024, 0, stream>>>(hbuf, done);
    k2_lstm<<<NBLOCKS, K2_THREADS, 0, stream>>>(
        x, w_ih0, w_hh0, b_ih0, b_hh0,
        w_ih1, w_hh1, b_ih1, b_hh1,
        w_ih2, w_hh2, b_ih2, b_hh2,
        hbuf, done);
    k3_logits<<<dim3(16, 20), 256, 0, stream>>>(hbuf, w_lin, b_lin, out);
    k4_logsoftmax<<<T_STEPS, 256, 0, stream>>>(out);
}

// Round 2
// 1997.686 us; speedup vs baseline: 2.9325x; 2.9325x over previous
//
#include <hip/hip_runtime.h>

#define HID 256
#define T_STEPS 1024
#define F_IN 40
#define NSPK 1251
#define NCHUNK 8            // workgroups per layer
#define NBLOCKS (3 * NCHUNK)
#define K2_THREADS 512

// workspace layout:
//   tagged h words: u64 hbuf[3][1025][256]   (tag = time index, low 32 = float bits)
//   plain float h2f[1024][256] for the logits GEMM
#define HBUF_WORDS (3 * 1025 * 256)
#define H2F_OFF_BYTES ((size_t)HBUF_WORDS * 8)

__device__ __forceinline__ float fast_sig(float v) {
    return __builtin_amdgcn_rcpf(1.f + __expf(-v));
}
__device__ __forceinline__ float fast_tanh(float v) {
    return 2.f * __builtin_amdgcn_rcpf(1.f + __expf(-2.f * v)) - 1.f;
}

// ---------------- K0: init h[l][0][:] = (tag 0 | 0.0f) ----------------
__global__ void k0_init(unsigned long long* __restrict__ hbuf) {
    int tid = threadIdx.x;
    if (tid < 3 * HID) {
        int l = tid / HID, k = tid % HID;
        hbuf[(size_t)(l * 1025 + 0) * HID + k] = 0ull;   // tag 0, value 0.0f
    }
}

// ---------------- K2: pipelined 3-layer LSTM, tagged-word sync ----------------
__global__ __launch_bounds__(K2_THREADS) void k2_lstm(
    const float* __restrict__ x,
    const float* __restrict__ w_ih0, const float* __restrict__ w_hh0,
    const float* __restrict__ b_ih0, const float* __restrict__ b_hh0,
    const float* __restrict__ w_ih1, const float* __restrict__ w_hh1,
    const float* __restrict__ b_ih1, const float* __restrict__ b_hh1,
    const float* __restrict__ w_ih2, const float* __restrict__ w_hh2,
    const float* __restrict__ b_ih2, const float* __restrict__ b_hh2,
    unsigned long long* __restrict__ hbuf, float* __restrict__ h2f)
{
    const int bid = blockIdx.x;
    const int layer = bid / NCHUNK;      // 0..2
    const int g     = bid % NCHUNK;      // chunk of 32 h-indices
    const int tid   = threadIdx.x;
    const int row_idx = tid >> 2;        // 0..127 : (gate q, local j)
    const int seg     = tid & 3;         // k-segment 0..3 (128 wide each)
    const int q  = row_idx >> 5;         // gate 0..3 (i,f,g,o)
    const int jj = row_idx & 31;
    const int r  = q * 256 + g * 32 + jj;  // global gate row 0..1023

    const float* wih = (layer == 0) ? w_ih0 : (layer == 1) ? w_ih1 : w_ih2;
    const float* whh = (layer == 0) ? w_hh0 : (layer == 1) ? w_hh1 : w_hh2;
    const float* bih = (layer == 0) ? b_ih0 : (layer == 1) ? b_ih1 : b_ih2;
    const float* bhh = (layer == 0) ? b_hh0 : (layer == 1) ? b_hh1 : b_hh2;

    __shared__ float lds_in[512];     // [0:256] = input vec (x row / prev-layer h), [256:512] = own h_prev
    __shared__ float lds_gate[128];

    // ---- load this thread's 128 weights into registers, pre-rotated by seg*8
    // floats so the LDS dot reads conflict-free (segs hit disjoint bank quads) ----
    float w[128];
    const int rot4 = 2 * seg;            // rotation in float4 units within the 32-float4 slice
    if (seg >= 2) {
        const float4* src = (const float4*)(whh + r * HID + (seg - 2) * 128);
        #pragma unroll
        for (int k4 = 0; k4 < 32; k4++) {
            float4 v = src[(k4 + rot4) & 31];
            w[k4 * 4 + 0] = v.x; w[k4 * 4 + 1] = v.y;
            w[k4 * 4 + 2] = v.z; w[k4 * 4 + 3] = v.w;
        }
    } else if (layer > 0) {
        const float4* src = (const float4*)(wih + r * HID + seg * 128);
        #pragma unroll
        for (int k4 = 0; k4 < 32; k4++) {
            float4 v = src[(k4 + rot4) & 31];
            w[k4 * 4 + 0] = v.x; w[k4 * 4 + 1] = v.y;
            w[k4 * 4 + 2] = v.z; w[k4 * 4 + 3] = v.w;
        }
    } else {
        // layer 0: seg0 holds the 40-wide x-projection row (rot=0), seg1 all-zero
        #pragma unroll
        for (int k = 0; k < 128; k++) w[k] = 0.f;
        if (seg == 0) {
            for (int k = 0; k < F_IN; k++) w[k] = w_ih0[r * F_IN + k];
        }
    }
    float bias = (seg == 0) ? (bih[r] + bhh[r]) : 0.f;

    for (int i = tid; i < 512; i += K2_THREADS) lds_in[i] = 0.f;
    __syncthreads();

    const float* x63 = x + 63 * T_STEPS * F_IN;
    const unsigned long long* h_prev_layer = hbuf + (size_t)(layer - 1) * 1025 * HID; // layer>0 only
    unsigned long long* h_own              = hbuf + (size_t)layer * 1025 * HID;

    float c_state = 0.f;   // valid for tid < 32 (h-index g*32+tid)

    for (int t = 0; t < T_STEPS; t++) {
        // ---- gather inputs: spin on tagged words, drop into LDS ----
        if (tid < 256) {
            // own-layer h[t], expected tag = t
            const unsigned long long* p = h_own + (size_t)t * HID + tid;
            unsigned long long v;
            do {
                v = __hip_atomic_load(p, __ATOMIC_RELAXED, __HIP_MEMORY_SCOPE_AGENT);
            } while ((unsigned)(v >> 32) != (unsigned)t);
            lds_in[256 + tid] = __uint_as_float((unsigned)v);
        } else if (layer > 0) {
            // prev-layer h[t+1], expected tag = t+1
            const unsigned long long* p = h_prev_layer + (size_t)(t + 1) * HID + (tid - 256);
            unsigned long long v;
            do {
                v = __hip_atomic_load(p, __ATOMIC_RELAXED, __HIP_MEMORY_SCOPE_AGENT);
            } while ((unsigned)(v >> 32) != (unsigned)(t + 1));
            lds_in[tid - 256] = __uint_as_float((unsigned)v);
        } else if (tid < 256 + 10) {
            // layer 0: stage x[63][t][:] (40 floats)
            ((float4*)lds_in)[tid - 256] = ((const float4*)(x63 + t * F_IN))[tid - 256];
        }
        __syncthreads();

        // ---- 128-wide partial dot per thread, weights in VGPRs, skewed LDS reads ----
        float acc = 0.f;
        const float* in = lds_in + seg * 128;
        const int rot = seg * 8;
        #pragma unroll
        for (int k4 = 0; k4 < 32; k4++) {
            int base = (k4 * 4 + rot) & 127;
            acc += w[k4 * 4 + 0] * in[base + 0];
            acc += w[k4 * 4 + 1] * in[base + 1];
            acc += w[k4 * 4 + 2] * in[base + 2];
            acc += w[k4 * 4 + 3] * in[base + 3];
        }
        acc += __shfl_xor(acc, 1, 64);
        acc += __shfl_xor(acc, 2, 64);
        if (seg == 0) lds_gate[row_idx] = acc + bias;
        __syncthreads();

        // ---- gate nonlinearity + state update + tagged publish (32 threads) ----
        if (tid < 32) {
            float gi = lds_gate[tid];
            float gf = lds_gate[32 + tid];
            float gg = lds_gate[64 + tid];
            float go = lds_gate[96 + tid];
            float si = fast_sig(gi);
            float sf = fast_sig(gf);
            float so = fast_sig(go);
            c_state = sf * c_state + si * fast_tanh(gg);
            float hv = so * fast_tanh(c_state);
            unsigned long long word =
                ((unsigned long long)(unsigned)(t + 1) << 32) | (unsigned long long)__float_as_uint(hv);
            __hip_atomic_store(h_own + (size_t)(t + 1) * HID + g * 32 + tid, word,
                               __ATOMIC_RELAXED, __HIP_MEMORY_SCOPE_AGENT);
            if (layer == 2) h2f[(size_t)t * HID + g * 32 + tid] = hv;
        }
        // no fence / flag needed: tag rides in the same atomic word
    }
}

// ---------------- K3: logits = h2 @ w_lin^T + b_lin (tiled fp32 GEMM) ----------------
#define BM 64
#define BN 64
#define BK 32
__global__ __launch_bounds__(256) void k3_logits(
    const float* __restrict__ A, const float* __restrict__ w_lin,
    const float* __restrict__ b_lin, float* __restrict__ out)
{
    int m0 = blockIdx.x * BM;
    int n0 = blockIdx.y * BN;
    int tid = threadIdx.x;
    __shared__ float As[BM][BK + 1];
    __shared__ float Bs[BN][BK + 1];
    float accv[4][4] = {};
    int tx = tid % 16, ty = tid / 16;

    for (int k0 = 0; k0 < HID; k0 += BK) {
        int row = tid / 4;
        int kq  = (tid % 4) * 8;
        {
            const float4* src = (const float4*)(A + (m0 + row) * HID + k0 + kq);
            float4 v0 = src[0], v1 = src[1];
            As[row][kq + 0] = v0.x; As[row][kq + 1] = v0.y; As[row][kq + 2] = v0.z; As[row][kq + 3] = v0.w;
            As[row][kq + 4] = v1.x; As[row][kq + 5] = v1.y; As[row][kq + 6] = v1.z; As[row][kq + 7] = v1.w;
        }
        {
            int n = n0 + row;
            float4 v0 = make_float4(0.f, 0.f, 0.f, 0.f), v1 = v0;
            if (n < NSPK) {
                const float4* src = (const float4*)(w_lin + n * HID + k0 + kq);
                v0 = src[0]; v1 = src[1];
            }
            Bs[row][kq + 0] = v0.x; Bs[row][kq + 1] = v0.y; Bs[row][kq + 2] = v0.z; Bs[row][kq + 3] = v0.w;
            Bs[row][kq + 4] = v1.x; Bs[row][kq + 5] = v1.y; Bs[row][kq + 6] = v1.z; Bs[row][kq + 7] = v1.w;
        }
        __syncthreads();
        #pragma unroll
        for (int kk = 0; kk < BK; kk++) {
            float a0 = As[ty * 4 + 0][kk], a1 = As[ty * 4 + 1][kk];
            float a2 = As[ty * 4 + 2][kk], a3 = As[ty * 4 + 3][kk];
            float b0 = Bs[tx * 4 + 0][kk], b1 = Bs[tx * 4 + 1][kk];
            float b2 = Bs[tx * 4 + 2][kk], b3 = Bs[tx * 4 + 3][kk];
            accv[0][0] += a0 * b0; accv[0][1] += a0 * b1; accv[0][2] += a0 * b2; accv[0][3] += a0 * b3;
            accv[1][0] += a1 * b0; accv[1][1] += a1 * b1; accv[1][2] += a1 * b2; accv[1][3] += a1 * b3;
            accv[2][0] += a2 * b0; accv[2][1] += a2 * b1; accv[2][2] += a2 * b2; accv[2][3] += a2 * b3;
            accv[3][0] += a3 * b0; accv[3][1] += a3 * b1; accv[3][2] += a3 * b2; accv[3][3] += a3 * b3;
        }
        __syncthreads();
    }
    #pragma unroll
    for (int i = 0; i < 4; i++) {
        int m = m0 + ty * 4 + i;
        #pragma unroll
        for (int j = 0; j < 4; j++) {
            int n = n0 + tx * 4 + j;
            if (n < NSPK) out[(size_t)m * NSPK + n] = accv[i][j] + b_lin[n];
        }
    }
}

// ---------------- K4: in-place row-wise log_softmax over NSPK ----------------
__global__ __launch_bounds__(256) void k4_logsoftmax(float* __restrict__ out)
{
    int t = blockIdx.x;
    float* row = out + (size_t)t * NSPK;
    int tid = threadIdx.x;
    __shared__ float red[8];
    float vals[5];
    float lmax = -1e30f;
    #pragma unroll
    for (int k = 0; k < 5; k++) {
        int n = tid + k * 256;
        vals[k] = (n < NSPK) ? row[n] : -1e30f;
        lmax = fmaxf(lmax, vals[k]);
    }
    #pragma unroll
    for (int m = 1; m < 64; m <<= 1) lmax = fmaxf(lmax, __shfl_xor(lmax, m, 64));
    int wave = tid >> 6;
    if ((tid & 63) == 0) red[wave] = lmax;
    __syncthreads();
    float gmax = fmaxf(fmaxf(red[0], red[1]), fmaxf(red[2], red[3]));
    float lsum = 0.f;
    #pragma unroll
    for (int k = 0; k < 5; k++) {
        int n = tid + k * 256;
        if (n < NSPK) lsum += __expf(vals[k] - gmax);
    }
    #pragma unroll
    for (int m = 1; m < 64; m <<= 1) lsum += __shfl_xor(lsum, m, 64);
    if ((tid & 63) == 0) red[4 + wave] = lsum;
    __syncthreads();
    float lse = logf(red[4] + red[5] + red[6] + red[7]) + gmax;
    #pragma unroll
    for (int k = 0; k < 5; k++) {
        int n = tid + k * 256;
        if (n < NSPK) row[n] = vals[k] - lse;
    }
}

extern "C" void kernel_launch(void* const* d_in, const int* in_sizes, int n_in,
                              void* d_out, int out_size, void* d_ws, size_t ws_size,
                              hipStream_t stream) {
    const float* x     = (const float*)d_in[0];
    const float* w_ih0 = (const float*)d_in[1];
    const float* w_hh0 = (const float*)d_in[2];
    const float* b_ih0 = (const float*)d_in[3];
    const float* b_hh0 = (const float*)d_in[4];
    const float* w_ih1 = (const float*)d_in[5];
    const float* w_hh1 = (const float*)d_in[6];
    const float* b_ih1 = (const float*)d_in[7];
    const float* b_hh1 = (const float*)d_in[8];
    const float* w_ih2 = (const float*)d_in[9];
    const float* w_hh2 = (const float*)d_in[10];
    const float* b_ih2 = (const float*)d_in[11];
    const float* b_hh2 = (const float*)d_in[12];
    const float* w_lin = (const float*)d_in[13];
    const float* b_lin = (const float*)d_in[14];

    unsigned long long* hbuf = (unsigned long long*)d_ws;
    float* h2f = (float*)((char*)d_ws + H2F_OFF_BYTES);
    float* out = (float*)d_out;

    k0_init<<<1, 1024, 0, stream>>>(hbuf);
    k2_lstm<<<NBLOCKS, K2_THREADS, 0, stream>>>(
        x, w_ih0, w_hh0, b_ih0, b_hh0,
        w_ih1, w_hh1, b_ih1, b_hh1,
        w_ih2, w_hh2, b_ih2, b_hh2,
        hbuf, h2f);
    k3_logits<<<dim3(16, 20), 256, 0, stream>>>(h2f, w_lin, b_lin, out);
    k4_logsoftmax<<<T_STEPS, 256, 0, stream>>>(out);
}